// Round 4
// baseline (393.786 us; speedup 1.0000x reference)
//
#include <hip/hip_runtime.h>

#define H 32
#define GPB 8   // 32-lane groups per 256-thread block

// tanh(x) = 1 - 2/(1 + exp2(x * 2*log2(e))); saturates correctly at +/-inf.
__device__ __forceinline__ float fast_tanh(float x) {
    float e = __builtin_amdgcn_exp2f(x * 2.8853900817779268f);
    float r = __builtin_amdgcn_rcpf(e + 1.0f);
    return fmaf(-2.0f, r, 1.0f);
}

// row_ror:K (K=1..15): lane i receives lane (i-K)&15 within its 16-lane row.
// Builtin path => compiler tracks the VALU-write -> DPP-read hazard.
template<int K>
__device__ __forceinline__ float rorK(float v) {
    return __int_as_float(__builtin_amdgcn_update_dpp(
        __float_as_int(v), __float_as_int(v), 0x120 | K, 0xf, 0xf, false));
}

// One rotation tap: t = ror<K>(V); hh-acc += t*W[K]; ro-acc += t*R[K].
#define PHK(K, V, W, R) { float tK = rorK<K>(V); \
    aAcc[K & 1] = fmaf(tK, W[K], aAcc[K & 1]); \
    rAcc[K & 1] = fmaf(tK, R[K], rAcc[K & 1]); }

// 16-tap phase over one 16-unit half of h (V = this lane's copy of the stream).
#define PHASE(V, W, R) \
    aAcc[0] = fmaf(V, W[0], aAcc[0]); rAcc[0] = fmaf(V, R[0], rAcc[0]); \
    PHK(1,V,W,R)  PHK(2,V,W,R)  PHK(3,V,W,R)  PHK(4,V,W,R)  PHK(5,V,W,R) \
    PHK(6,V,W,R)  PHK(7,V,W,R)  PHK(8,V,W,R)  PHK(9,V,W,R)  PHK(10,V,W,R) \
    PHK(11,V,W,R) PHK(12,V,W,R) PHK(13,V,W,R) PHK(14,V,W,R) PHK(15,V,W,R)

#define SWIZ_XOR16 0x401F   // BitMode: xor_mask=16, and_mask=0x1F (within 32-lane half)

__global__ __launch_bounds__(256, 1) void rnn_fused(
    const float* __restrict__ onehot,   // [B,T,4]
    const float* __restrict__ rewards,  // [B,T]
    const float* __restrict__ W_ih,     // [H,5]
    const float* __restrict__ W_hh,     // [H,H]
    const float* __restrict__ b_ih,     // [H]
    const float* __restrict__ b_hh,     // [H]
    const float* __restrict__ W_ro,     // [4,H]
    const float* __restrict__ b_ro,     // [4]
    float* __restrict__ out_logits,     // [B,T,4]
    float* __restrict__ out_hT,         // [B,H]
    int T)
{
    const int tid = threadIdx.x;
    const int u = tid & 31;              // hidden unit owned by this lane
    const int g = tid >> 5;              // group (batch element) in block
    const int b = blockIdx.x * GPB + g;
    const int i = u & 15;                // index within 16-lane DPP row
    const int r = u >> 4;                // which row of the group this lane is in
    const int a = u & 3;                 // readout row this lane accumulates

    // ---- per-lane weights, pre-rotated to match the row_ror:k stream ----
    // At tap k this lane sees h_{16*r + ((i-k)&15)} (phase A, own copy)
    // and h_{16*(1-r) + ((i-k)&15)} (phase B, swizzle-mirrored copy).
    float wA[16], wB[16], roA[16], roB[16];
#pragma unroll
    for (int k = 0; k < 16; ++k) {
        int col = (i - k) & 15;
        wA[k]  = W_hh[u * H + 16 * r       + col];
        wB[k]  = W_hh[u * H + 16 * (1 - r) + col];
        roA[k] = W_ro[a * H + 16 * r       + col];
        roB[k] = W_ro[a * H + 16 * (1 - r) + col];
    }
    const float wih0 = W_ih[u*5+0], wih1 = W_ih[u*5+1], wih2 = W_ih[u*5+2],
                wih3 = W_ih[u*5+3], wih4 = W_ih[u*5+4];
    const float bias = b_ih[u] + b_hh[u];
    const float bro  = b_ro[a];

    const float* oh_ptr = onehot  + (size_t)b * T * 4;
    const float* rw_ptr = rewards + (size_t)b * T;
    float*       lg_ptr = out_logits + (size_t)b * T * 4;

    // ---- 4-step-deep x prefetch ring ----
    float4 oh0 = *(const float4*)(oh_ptr + 0);
    float4 oh1 = *(const float4*)(oh_ptr + 4);
    float4 oh2 = *(const float4*)(oh_ptr + 8);
    float4 oh3 = *(const float4*)(oh_ptr + 12);
    float4 rw  = *(const float4*)(rw_ptr);

    float hj = 0.0f;                     // h^{(-1)} = 0

    // step t: stream h^{(t-1)} across the group via DPP (own row) + one
    // ds_swizzle xor-16 (other row); fold W_hh matvec and W_ro readout into
    // the same stream; logits_{t-1} emitted (lag-1 for free); then
    // h^{(t)} = tanh(xp_t + W_hh h^{(t-1)}).
    auto step = [&](float xp, int tm1, bool wr) {
        int mi = __builtin_amdgcn_ds_swizzle(__float_as_int(hj), SWIZ_XOR16);
        float aAcc[2] = {xp, 0.f};
        float rAcc[2] = {0.f, 0.f};
        PHASE(hj, wA, roA);              // covers units 16r .. 16r+15
        float m = __int_as_float(mi);    // lgkm wait lands here (hidden by phase A)
        PHASE(m, wB, roB);               // covers units 16(1-r) .. +15
        hj = fast_tanh(aAcc[0] + aAcc[1]);
        if (wr && u < 4)
            lg_ptr[(size_t)tm1 * 4 + u] = (rAcc[0] + rAcc[1]) + bro;
    };

    // ---- peeled first block (t = 0..3): no logits for t-1 = -1 ----
    {
        float xp0 = fmaf(oh0.x,wih0, fmaf(oh0.y,wih1, fmaf(oh0.z,wih2, fmaf(oh0.w,wih3, fmaf(rw.x,wih4, bias)))));
        float xp1 = fmaf(oh1.x,wih0, fmaf(oh1.y,wih1, fmaf(oh1.z,wih2, fmaf(oh1.w,wih3, fmaf(rw.y,wih4, bias)))));
        float xp2 = fmaf(oh2.x,wih0, fmaf(oh2.y,wih1, fmaf(oh2.z,wih2, fmaf(oh2.w,wih3, fmaf(rw.z,wih4, bias)))));
        float xp3 = fmaf(oh3.x,wih0, fmaf(oh3.y,wih1, fmaf(oh3.z,wih2, fmaf(oh3.w,wih3, fmaf(rw.w,wih4, bias)))));
        oh0 = *(const float4*)(oh_ptr + 16);
        oh1 = *(const float4*)(oh_ptr + 20);
        oh2 = *(const float4*)(oh_ptr + 24);
        oh3 = *(const float4*)(oh_ptr + 28);
        rw  = *(const float4*)(rw_ptr + 4);
        step(xp0, -1, false);
        step(xp1,  0, true);
        step(xp2,  1, true);
        step(xp3,  2, true);
    }

    for (int tb = 4; tb < T; tb += 4) {
        float xp0 = fmaf(oh0.x,wih0, fmaf(oh0.y,wih1, fmaf(oh0.z,wih2, fmaf(oh0.w,wih3, fmaf(rw.x,wih4, bias)))));
        float xp1 = fmaf(oh1.x,wih0, fmaf(oh1.y,wih1, fmaf(oh1.z,wih2, fmaf(oh1.w,wih3, fmaf(rw.y,wih4, bias)))));
        float xp2 = fmaf(oh2.x,wih0, fmaf(oh2.y,wih1, fmaf(oh2.z,wih2, fmaf(oh2.w,wih3, fmaf(rw.z,wih4, bias)))));
        float xp3 = fmaf(oh3.x,wih0, fmaf(oh3.y,wih1, fmaf(oh3.z,wih2, fmaf(oh3.w,wih3, fmaf(rw.w,wih4, bias)))));
        if (tb + 4 < T) {
            oh0 = *(const float4*)(oh_ptr + (size_t)(tb + 4) * 4);
            oh1 = *(const float4*)(oh_ptr + (size_t)(tb + 5) * 4);
            oh2 = *(const float4*)(oh_ptr + (size_t)(tb + 6) * 4);
            oh3 = *(const float4*)(oh_ptr + (size_t)(tb + 7) * 4);
            rw  = *(const float4*)(rw_ptr + tb + 4);
        }
        step(xp0, tb - 1, true);
        step(xp1, tb + 0, true);
        step(xp2, tb + 1, true);
        step(xp3, tb + 2, true);
    }

    // ---- epilogue: logits_{T-1} from h^{(T-1)} (readout-only pass) ----
    {
        int mi = __builtin_amdgcn_ds_swizzle(__float_as_int(hj), SWIZ_XOR16);
        float aAcc[2] = {0.f, 0.f};      // dummy hh accs (unused)
        float rAcc[2] = {0.f, 0.f};
        PHASE(hj, wA, roA);
        float m = __int_as_float(mi);
        PHASE(m, wB, roB);
        (void)aAcc;
        if (u < 4)
            lg_ptr[(size_t)(T - 1) * 4 + u] = (rAcc[0] + rAcc[1]) + bro;
    }
    out_hT[(size_t)b * H + u] = hj;      // h_T

}

extern "C" void kernel_launch(void* const* d_in, const int* in_sizes, int n_in,
                              void* d_out, int out_size, void* d_ws, size_t ws_size,
                              hipStream_t stream) {
    const float* onehot  = (const float*)d_in[0];
    const float* rewards = (const float*)d_in[1];
    const float* W_ih    = (const float*)d_in[2];
    const float* W_hh    = (const float*)d_in[3];
    const float* b_ih    = (const float*)d_in[4];
    const float* b_hh    = (const float*)d_in[5];
    const float* W_ro    = (const float*)d_in[6];
    const float* b_ro    = (const float*)d_in[7];

    const int T = 1024;                  // per setup_inputs()
    const int B = in_sizes[1] / T;       // in_sizes[1] = B*T

    float* out_logits = (float*)d_out;                        // [B,T,4]
    float* out_hT     = (float*)d_out + (size_t)B * T * 4;    // [B,H]

    dim3 block(256);
    dim3 grid(B / GPB);
    rnn_fused<<<grid, block, 0, stream>>>(onehot, rewards, W_ih, W_hh,
                                          b_ih, b_hh, W_ro, b_ro,
                                          out_logits, out_hT, T);
}